// Round 13
// baseline (1668.999 us; speedup 1.0000x reference)
//
#include <hip/hip_runtime.h>
#include <hip/hip_bf16.h>

namespace {
constexpr int Md = 4096, Kd = 4096, Nd = 12288;
constexpr int BM = 256, BN = 128, BK = 64;
constexpr int TK = Kd / BK;                        // 64
constexpr int THREADS = 512;
constexpr size_t A_BYTES = (size_t)Md * Kd * 2;    // fp16 copy of X in d_ws
constexpr int AS_T = BM * BK;                      // 16384 shorts (32 KB)
constexpr int BS_T = BN * BK;                      // 8192 shorts  (16 KB)
constexpr int LDS_BYTES = (AS_T + BS_T) * 2;       // 49152 -> 3 blocks/CU (24 waves)

typedef __attribute__((ext_vector_type(4))) float f4;
typedef __attribute__((ext_vector_type(8))) _Float16 h8;
typedef __attribute__((ext_vector_type(2))) _Float16 h2;

constexpr unsigned M4  = 0x000F000Fu;
constexpr unsigned MAG = 0x64006400u;              // fp16 1024.0 both halves

__device__ __forceinline__ unsigned pkrtz(float lo, float hi) {
  return __builtin_bit_cast(unsigned, __builtin_amdgcn_cvt_pkrtz(lo, hi));
}

// X -> fp16, k-permuted [0,4,1,5,2,6,3,7] per 8-chunk (matches magic-dequant
// emission order; identical permutation on A and B leaves the product exact).
__global__ __launch_bounds__(256)
void cvtA_perm(const float* __restrict__ X, unsigned short* __restrict__ Xb, int n8) {
  int i = blockIdx.x * blockDim.x + threadIdx.x;
  const int stride = gridDim.x * blockDim.x;
  for (; i < n8; i += stride) {
    const f4* p = (const f4*)X + (size_t)i * 2;
    f4 a = p[0], b = p[1];
    uint4 o;
    o.x = pkrtz(a[0], b[0]); o.y = pkrtz(a[1], b[1]);
    o.z = pkrtz(a[2], b[2]); o.w = pkrtz(a[3], b[3]);
    ((uint4*)Xb)[i] = o;
  }
}

// ---- main: r6 kernel, SINGLE-buffered A+B, 48 KB LDS -> 3 blocks/CU.
// Cross-block phase overlap (n=3) covers the serial stage phase; per-block
// schedule is the proven 2-barrier loop with QW/scale register prefetch.
template<bool AWS>
__global__ __launch_bounds__(THREADS, 6)
void qgemm13(const float* __restrict__ X, const unsigned short* __restrict__ Xb,
             const int* __restrict__ QW, const int* __restrict__ QZ,
             const float* __restrict__ SC, const float* __restrict__ BS,
             float* __restrict__ OUT)
{
  extern __shared__ char smem[];
  unsigned short* As = (unsigned short*)smem;                  // [AS_T]
  unsigned short* Bs = (unsigned short*)(smem + AS_T * 2);     // [BS_T]

  const int nwg = gridDim.x, cpx = nwg >> 3, b = blockIdx.x;
  const int swz = (b & 7) * cpx + (b >> 3);       // 1536 % 8 == 0 -> bijective
  const int bm = swz / (Nd / BN), bn = swz % (Nd / BN);  // bm-major: X panel L2-resident
  const int m0 = bm * BM, n0 = bn * BN;

  const int tid = threadIdx.x, lane = tid & 63, wid = tid >> 6;
  const int wr = wid >> 1, wc = wid & 1;          // 4x2 waves, each 64x64
  const int n_l = tid & 127;                      // B staging: n within tile
  const int k8b = (tid >> 7) * 2;                 // first of 2 k8-rows
  const int nab = n0 + n_l;

  f4 acc[4][4];
  #pragma unroll
  for (int i = 0; i < 4; ++i)
    #pragma unroll
    for (int j = 0; j < 4; ++j) acc[i][j] = {0.0f, 0.0f, 0.0f, 0.0f};

  // --- A staging: linear LDS dest, pre-swizzled global source (kb ^ (r&7)) ---
  auto stageA = [&](int t) {
    #pragma unroll
    for (int i = 0; i < 4; ++i) {
      const int c = i * THREADS + tid;            // 2048 chunks = 256 rows x 8 kb
      const int r = c >> 3, kbl = c & 7;
      const unsigned short* src = Xb + (size_t)(m0 + r) * Kd + t * BK + ((kbl ^ (r & 7)) << 3);
      __builtin_amdgcn_global_load_lds(
          (const __attribute__((address_space(1))) unsigned*)src,
          (__attribute__((address_space(3))) unsigned*)(As + c * 8),
          16, 0, 0);
    }
  };
  auto stageA_f = [&](int t) {                    // fallback: fp32 + pkrtz permute
    #pragma unroll
    for (int i = 0; i < 4; ++i) {
      const int c = i * THREADS + tid;
      const int r = c >> 3, kbl = c & 7;
      const f4* src = (const f4*)(X + (size_t)(m0 + r) * Kd + t * BK + ((kbl ^ (r & 7)) << 3));
      f4 a = src[0], bb = src[1];
      uint4 o;
      o.x = pkrtz(a[0], bb[0]); o.y = pkrtz(a[1], bb[1]);
      o.z = pkrtz(a[2], bb[2]); o.w = pkrtz(a[3], bb[3]);
      *(uint4*)(As + c * 8) = o;
    }
  };

  // --- B: packed words + scale/zero -> fp16x2 constants (register prefetch) ---
  auto loadB = [&](int t, int* w, unsigned& hs2, unsigned& hz2) {
    const int* qp = QW + (size_t)(t * 8 + k8b) * Nd + nab;
    w[0] = qp[0];
    w[1] = qp[Nd];
    const int g = t >> 1;                         // BK=64: group constant per tile
    const float s = SC[(size_t)g * Nd + nab];
    const int z32 = QZ[(size_t)g * (Nd / 8) + (nab >> 3)];
    const int z = (z32 >> ((nab & 7) * 4)) & 15;
    hz2 = (0x6400u + (unsigned)z + 1u) * 0x10001u;    // fp16(1025+z), exact
    hs2 = (unsigned)__builtin_bit_cast(unsigned short, (_Float16)s) * 0x10001u;
  };
  auto writeB = [&](const int* w, unsigned hs2, unsigned hz2) {
    const h2 vz = __builtin_bit_cast(h2, hz2);
    const h2 vs = __builtin_bit_cast(h2, hs2);
    #pragma unroll
    for (int i = 0; i < 2; ++i) {
      const unsigned q = (unsigned)w[i];
      const int k8 = k8b + i;
      const unsigned p0 = (q & M4) | MAG;
      const unsigned p1 = ((q >> 4) & M4) | MAG;
      const unsigned p2 = ((q >> 8) & M4) | MAG;
      const unsigned p3 = ((q >> 12) & M4) | MAG;
      const h2 f0 = (__builtin_bit_cast(h2, p0) - vz) * vs;
      const h2 f1 = (__builtin_bit_cast(h2, p1) - vz) * vs;
      const h2 f2 = (__builtin_bit_cast(h2, p2) - vz) * vs;
      const h2 f3 = (__builtin_bit_cast(h2, p3) - vz) * vs;
      uint4 o;
      o.x = __builtin_bit_cast(unsigned, f0);
      o.y = __builtin_bit_cast(unsigned, f1);
      o.z = __builtin_bit_cast(unsigned, f2);
      o.w = __builtin_bit_cast(unsigned, f3);
      *(uint4*)(Bs + n_l * BK + ((k8 ^ (n_l & 7)) << 3)) = o;
    }
  };
  auto mfma_tile = [&]() {
    #pragma unroll
    for (int ks = 0; ks < 2; ++ks) {
      h8 af[4], bf[4];
      const int kb = ks * 4 + (lane >> 4);
      #pragma unroll
      for (int mi = 0; mi < 4; ++mi) {
        const int r = wr * 64 + mi * 16 + (lane & 15);
        af[mi] = *(const h8*)&As[r * BK + ((kb ^ (r & 7)) << 3)];
      }
      #pragma unroll
      for (int ni = 0; ni < 4; ++ni) {
        const int cc = wc * 64 + ni * 16 + (lane & 15);
        bf[ni] = *(const h8*)&Bs[cc * BK + ((kb ^ (cc & 7)) << 3)];
      }
      #pragma unroll
      for (int mi = 0; mi < 4; ++mi)
        #pragma unroll
        for (int ni = 0; ni < 4; ++ni)
          acc[mi][ni] = __builtin_amdgcn_mfma_f32_16x16x32_f16(af[mi], bf[ni], acc[mi][ni], 0, 0, 0);
    }
  };

  int bw[2]; unsigned sHS, sHZ;
  int nbw[2]; unsigned nHS, nHZ;

  // prologue: tile 0 fully staged
  loadB(0, bw, sHS, sHZ);
  if constexpr (AWS) stageA(0); else stageA_f(0);
  writeB(bw, sHS, sHZ);
  __syncthreads();                                 // A0 + B0 visible

  for (int t = 0; t < TK; ++t) {
    if (t + 1 < TK) loadB(t + 1, nbw, nHS, nHZ);   // global prefetch under MFMA
    mfma_tile();
    __syncthreads();                               // reads of tile t done
    if (t + 1 < TK) {
      if constexpr (AWS) stageA(t + 1); else stageA_f(t + 1);
      writeB(nbw, nHS, nHZ);                       // dequant tile t+1
    }
    __syncthreads();                               // staging complete
  }

  // epilogue: C/D layout col = lane&15, row = (lane>>4)*4 + j
  #pragma unroll
  for (int ni = 0; ni < 4; ++ni) {
    const int gn = n0 + wc * 64 + ni * 16 + (lane & 15);
    const float bv = BS[gn];
    #pragma unroll
    for (int mi = 0; mi < 4; ++mi) {
      const int gm = m0 + wr * 64 + mi * 16 + ((lane >> 4) << 2);
      #pragma unroll
      for (int j = 0; j < 4; ++j)
        OUT[(size_t)(gm + j) * Nd + gn] = acc[mi][ni][j] + bv;
    }
  }
}
} // namespace

extern "C" void kernel_launch(void* const* d_in, const int* in_sizes, int n_in,
                              void* d_out, int out_size, void* d_ws, size_t ws_size,
                              hipStream_t stream) {
  const float* x  = (const float*)d_in[0];
  const int*   qw = (const int*)d_in[1];
  const int*   qz = (const int*)d_in[2];
  const float* sc = (const float*)d_in[3];
  const float* bs = (const float*)d_in[4];
  float* out = (float*)d_out;

  (void)hipFuncSetAttribute((const void*)qgemm13<true>,
                            hipFuncAttributeMaxDynamicSharedMemorySize, LDS_BYTES);
  (void)hipFuncSetAttribute((const void*)qgemm13<false>,
                            hipFuncAttributeMaxDynamicSharedMemorySize, LDS_BYTES);

  dim3 grid((Md / BM) * (Nd / BN));   // 16 * 96 = 1536
  if (ws_size >= A_BYTES) {
    unsigned short* xh = (unsigned short*)d_ws;
    const int n8 = Md * Kd / 8;
    cvtA_perm<<<2048, 256, 0, stream>>>(x, xh, n8);
    qgemm13<true><<<grid, dim3(THREADS), LDS_BYTES, stream>>>(x, xh, qw, qz, sc, bs, out);
  } else {
    qgemm13<false><<<grid, dim3(THREADS), LDS_BYTES, stream>>>(x, nullptr, qw, qz, sc, bs, out);
  }
}

// Round 14
// 438.357 us; speedup vs baseline: 3.8074x; 3.8074x over previous
//
#include <hip/hip_runtime.h>
#include <hip/hip_bf16.h>

namespace {
constexpr int Md = 4096, Kd = 4096, Nd = 12288;
constexpr int BM = 256, BN = 128, BK = 64;
constexpr int TK = Kd / BK;                        // 64
constexpr int THREADS = 512;
constexpr size_t A_BYTES = (size_t)Md * Kd * 2;    // fp16 copy of X in d_ws
constexpr int AS_T = BM * BK;                      // 16384 shorts (32 KB / buf)
constexpr int BS_T = BN * BK;                      // 8192 shorts  (16 KB)
constexpr int LDS_BYTES = (2 * AS_T + BS_T) * 2;   // 81920 -> 2 blocks/CU

typedef __attribute__((ext_vector_type(4))) float f4;
typedef __attribute__((ext_vector_type(8))) _Float16 h8;
typedef __attribute__((ext_vector_type(2))) _Float16 h2;

constexpr unsigned M4  = 0x000F000Fu;
constexpr unsigned MAG = 0x64006400u;              // fp16 1024.0 in both halves

__device__ __forceinline__ unsigned pkrtz(float lo, float hi) {
  return __builtin_bit_cast(unsigned, __builtin_amdgcn_cvt_pkrtz(lo, hi));
}

// X -> fp16, k-permuted [0,4,1,5,2,6,3,7] per 8-chunk (matches magic-dequant
// emission order for B; MFMA sums over k, so identical permutation on A and B
// leaves the product exact).
__global__ __launch_bounds__(256)
void cvtA_perm(const float* __restrict__ X, unsigned short* __restrict__ Xb, int n8) {
  int i = blockIdx.x * blockDim.x + threadIdx.x;
  const int stride = gridDim.x * blockDim.x;
  for (; i < n8; i += stride) {
    const f4* p = (const f4*)X + (size_t)i * 2;
    f4 a = p[0], b = p[1];
    uint4 o;
    o.x = pkrtz(a[0], b[0]); o.y = pkrtz(a[1], b[1]);
    o.z = pkrtz(a[2], b[2]); o.w = pkrtz(a[3], b[3]);
    ((uint4*)Xb)[i] = o;
  }
}

// r6 champion structure: 2 blocks/CU, A double-buffered via global_load_lds,
// B single-buffered inline magic-dequant, 2 barriers/K-step.
// This round's single change: s_setprio(1/0) around the MFMA cluster (T5) —
// cross-block phase diversity lets the MFMA-phase block preempt the staging block.
template<bool AWS>
__global__ __launch_bounds__(THREADS, 4)
void qgemm14(const float* __restrict__ X, const unsigned short* __restrict__ Xb,
             const int* __restrict__ QW, const int* __restrict__ QZ,
             const float* __restrict__ SC, const float* __restrict__ BS,
             float* __restrict__ OUT)
{
  extern __shared__ char smem[];
  unsigned short* As = (unsigned short*)smem;                      // [2][AS_T]
  unsigned short* Bs = (unsigned short*)(smem + 2 * AS_T * 2);     // [BS_T]

  const int nwg = gridDim.x, cpx = nwg >> 3, b = blockIdx.x;
  const int swz = (b & 7) * cpx + (b >> 3);       // 1536 % 8 == 0 -> bijective
  const int bm = swz / (Nd / BN), bn = swz % (Nd / BN);  // bm-major: X panel L2-resident
  const int m0 = bm * BM, n0 = bn * BN;

  const int tid = threadIdx.x, lane = tid & 63, wid = tid >> 6;
  const int wr = wid >> 1, wc = wid & 1;          // 4x2 waves, each 64x64
  const int n_l = tid & 127;
  const int k8b = (tid >> 7) * 2;                 // first of 2 k8-rows
  const int nab = n0 + n_l;

  f4 acc[4][4];
  #pragma unroll
  for (int i = 0; i < 4; ++i)
    #pragma unroll
    for (int j = 0; j < 4; ++j) acc[i][j] = {0.0f, 0.0f, 0.0f, 0.0f};

  // --- A staging: linear LDS dest, pre-swizzled global source (kb ^ (r&7)) ---
  auto stageA = [&](int t, int buf) {
    #pragma unroll
    for (int i = 0; i < 4; ++i) {
      const int c = i * THREADS + tid;            // 16B chunk index
      const int r = c >> 3, kbl = c & 7;
      const unsigned short* src = Xb + (size_t)(m0 + r) * Kd + t * BK + ((kbl ^ (r & 7)) << 3);
      __builtin_amdgcn_global_load_lds(
          (const __attribute__((address_space(1))) unsigned*)src,
          (__attribute__((address_space(3))) unsigned*)(As + buf * AS_T + c * 8),
          16, 0, 0);
    }
  };
  auto stageA_f = [&](int t, int buf) {           // fallback: fp32 + pkrtz permute
    #pragma unroll
    for (int i = 0; i < 4; ++i) {
      const int c = i * THREADS + tid;
      const int r = c >> 3, kbl = c & 7;
      const f4* src = (const f4*)(X + (size_t)(m0 + r) * Kd + t * BK + ((kbl ^ (r & 7)) << 3));
      f4 a = src[0], bb = src[1];
      uint4 o;
      o.x = pkrtz(a[0], bb[0]); o.y = pkrtz(a[1], bb[1]);
      o.z = pkrtz(a[2], bb[2]); o.w = pkrtz(a[3], bb[3]);
      *(uint4*)(As + buf * AS_T + c * 8) = o;
    }
  };

  // --- B: packed words + scale/zero -> fp16x2 constants ---
  auto loadB = [&](int t, int* w, unsigned& hs2, unsigned& hz2) {
    const int* qp = QW + (size_t)(t * 8 + k8b) * Nd + nab;
    w[0] = qp[0];
    w[1] = qp[Nd];
    const int g = t >> 1;                         // BK=64: group constant per tile
    const float s = SC[(size_t)g * Nd + nab];
    const int z32 = QZ[(size_t)g * (Nd / 8) + (nab >> 3)];
    const int z = (z32 >> ((nab & 7) * 4)) & 15;
    hz2 = (0x6400u + (unsigned)z + 1u) * 0x10001u;    // fp16(1025+z), exact
    hs2 = (unsigned)__builtin_bit_cast(unsigned short, (_Float16)s) * 0x10001u;
  };
  auto writeB = [&](const int* w, unsigned hs2, unsigned hz2) {
    const h2 vz = __builtin_bit_cast(h2, hz2);
    const h2 vs = __builtin_bit_cast(h2, hs2);
    #pragma unroll
    for (int i = 0; i < 2; ++i) {
      const unsigned q = (unsigned)w[i];
      const int k8 = k8b + i;
      const unsigned p0 = (q & M4) | MAG;
      const unsigned p1 = ((q >> 4) & M4) | MAG;
      const unsigned p2 = ((q >> 8) & M4) | MAG;
      const unsigned p3 = ((q >> 12) & M4) | MAG;
      const h2 f0 = (__builtin_bit_cast(h2, p0) - vz) * vs;
      const h2 f1 = (__builtin_bit_cast(h2, p1) - vz) * vs;
      const h2 f2 = (__builtin_bit_cast(h2, p2) - vz) * vs;
      const h2 f3 = (__builtin_bit_cast(h2, p3) - vz) * vs;
      uint4 o;
      o.x = __builtin_bit_cast(unsigned, f0);
      o.y = __builtin_bit_cast(unsigned, f1);
      o.z = __builtin_bit_cast(unsigned, f2);
      o.w = __builtin_bit_cast(unsigned, f3);
      *(uint4*)(Bs + n_l * BK + ((k8 ^ (n_l & 7)) << 3)) = o;
    }
  };

  auto mfma_tile = [&](int cb) {
    const unsigned short* Ab = As + cb * AS_T;
    #pragma unroll
    for (int ks = 0; ks < 2; ++ks) {
      h8 af[4], bf[4];
      const int kb = ks * 4 + (lane >> 4);
      #pragma unroll
      for (int mi = 0; mi < 4; ++mi) {
        const int r = wr * 64 + mi * 16 + (lane & 15);
        af[mi] = *(const h8*)&Ab[r * BK + ((kb ^ (r & 7)) << 3)];
      }
      #pragma unroll
      for (int ni = 0; ni < 4; ++ni) {
        const int cc = wc * 64 + ni * 16 + (lane & 15);
        bf[ni] = *(const h8*)&Bs[cc * BK + ((kb ^ (cc & 7)) << 3)];
      }
      __builtin_amdgcn_s_setprio(1);             // T5: favor MFMA-phase waves
      #pragma unroll
      for (int mi = 0; mi < 4; ++mi)
        #pragma unroll
        for (int ni = 0; ni < 4; ++ni)
          acc[mi][ni] = __builtin_amdgcn_mfma_f32_16x16x32_f16(af[mi], bf[ni], acc[mi][ni], 0, 0, 0);
      __builtin_amdgcn_s_setprio(0);
    }
  };

  int bw[2]; unsigned sHS, sHZ;
  int nbw[2]; unsigned nHS, nHZ;

  // prologue: tile 0
  if constexpr (AWS) stageA(0, 0); else stageA_f(0, 0);
  loadB(0, bw, sHS, sHZ);
  writeB(bw, sHS, sHZ);
  __syncthreads();                                 // A0 + B0 visible

  for (int t = 0; t < TK; ++t) {
    const int cb = t & 1;
    if (t + 1 < TK) {
      if constexpr (AWS) stageA(t + 1, cb ^ 1);    // DMA in flight across MFMA
      loadB(t + 1, nbw, nHS, nHZ);
    }
    mfma_tile(cb);
    __syncthreads();                               // Bs reads done (other block covers drain)
    if (t + 1 < TK) {
      if constexpr (!AWS) stageA_f(t + 1, cb ^ 1);
      writeB(nbw, nHS, nHZ);                       // dequant tile t+1 into Bs
    }
    __syncthreads();                               // Bs + A writes visible
  }

  // epilogue: C/D layout col = lane&15, row = (lane>>4)*4 + j
  #pragma unroll
  for (int ni = 0; ni < 4; ++ni) {
    const int gn = n0 + wc * 64 + ni * 16 + (lane & 15);
    const float bv = BS[gn];
    #pragma unroll
    for (int mi = 0; mi < 4; ++mi) {
      const int gm = m0 + wr * 64 + mi * 16 + ((lane >> 4) << 2);
      #pragma unroll
      for (int j = 0; j < 4; ++j)
        OUT[(size_t)(gm + j) * Nd + gn] = acc[mi][ni][j] + bv;
    }
  }
}
} // namespace

extern "C" void kernel_launch(void* const* d_in, const int* in_sizes, int n_in,
                              void* d_out, int out_size, void* d_ws, size_t ws_size,
                              hipStream_t stream) {
  const float* x  = (const float*)d_in[0];
  const int*   qw = (const int*)d_in[1];
  const int*   qz = (const int*)d_in[2];
  const float* sc = (const float*)d_in[3];
  const float* bs = (const float*)d_in[4];
  float* out = (float*)d_out;

  (void)hipFuncSetAttribute((const void*)qgemm14<true>,
                            hipFuncAttributeMaxDynamicSharedMemorySize, LDS_BYTES);
  (void)hipFuncSetAttribute((const void*)qgemm14<false>,
                            hipFuncAttributeMaxDynamicSharedMemorySize, LDS_BYTES);

  dim3 grid((Md / BM) * (Nd / BN));   // 16 * 96 = 1536
  if (ws_size >= A_BYTES) {
    unsigned short* xh = (unsigned short*)d_ws;
    const int n8 = Md * Kd / 8;
    cvtA_perm<<<2048, 256, 0, stream>>>(x, xh, n8);
    qgemm14<true><<<grid, dim3(THREADS), LDS_BYTES, stream>>>(x, xh, qw, qz, sc, bs, out);
  } else {
    qgemm14<false><<<grid, dim3(THREADS), LDS_BYTES, stream>>>(x, nullptr, qw, qz, sc, bs, out);
  }
}

// Round 15
// 400.497 us; speedup vs baseline: 4.1673x; 1.0945x over previous
//
#include <hip/hip_runtime.h>
#include <hip/hip_bf16.h>

namespace {
constexpr int Md = 4096, Kd = 4096, Nd = 12288;
constexpr int BM = 256, BN = 256, BK = 64;
constexpr int TK = Kd / BK;                        // 64
constexpr int THREADS = 512;                       // 8 waves, 2M x 4N, 128x64 each
constexpr size_t A_BYTES = (size_t)Md * Kd * 2;    // fp16 copy of X in d_ws
constexpr int AS_T = BM * BK;                      // 16384 shorts (32 KB / buf)
constexpr int BS_T = BN * BK;                      // 16384 shorts (32 KB / buf)
constexpr int LDS_BYTES = (2 * AS_T + 2 * BS_T) * 2;   // 131072 -> 1 block/CU

typedef __attribute__((ext_vector_type(4))) float f4;
typedef __attribute__((ext_vector_type(8))) _Float16 h8;
typedef __attribute__((ext_vector_type(2))) _Float16 h2;

constexpr unsigned M4  = 0x000F000Fu;
constexpr unsigned MAG = 0x64006400u;              // fp16 1024.0 both halves

#define SBAR       asm volatile("s_barrier" ::: "memory")
#define WAIT_LGKM0 asm volatile("s_waitcnt lgkmcnt(0)" ::: "memory")
#define WAIT_VM0   asm volatile("s_waitcnt vmcnt(0)" ::: "memory")

__device__ __forceinline__ unsigned pkrtz(float lo, float hi) {
  return __builtin_bit_cast(unsigned, __builtin_amdgcn_cvt_pkrtz(lo, hi));
}

// X -> fp16, k-permuted [0,4,1,5,2,6,3,7] per 8-chunk (matches magic-dequant
// emission order; identical permutation on A and B leaves the product exact).
__global__ __launch_bounds__(256)
void cvtA_perm(const float* __restrict__ X, unsigned short* __restrict__ Xb, int n8) {
  int i = blockIdx.x * blockDim.x + threadIdx.x;
  const int stride = gridDim.x * blockDim.x;
  for (; i < n8; i += stride) {
    const f4* p = (const f4*)X + (size_t)i * 2;
    f4 a = p[0], b = p[1];
    uint4 o;
    o.x = pkrtz(a[0], b[0]); o.y = pkrtz(a[1], b[1]);
    o.z = pkrtz(a[2], b[2]); o.w = pkrtz(a[3], b[3]);
    ((uint4*)Xb)[i] = o;
  }
}

// ---------------- main: 256x256 8-phase schedule, inline int4 dequant ----------------
__global__ __launch_bounds__(THREADS, 2)
void qgemm8(const unsigned short* __restrict__ Xb,
            const int* __restrict__ QW, const int* __restrict__ QZ,
            const float* __restrict__ SC, const float* __restrict__ BS,
            float* __restrict__ OUT)
{
  extern __shared__ char smem[];
  unsigned short* As = (unsigned short*)smem;                      // [2][AS_T]
  unsigned short* Bs = (unsigned short*)(smem + 2 * AS_T * 2);     // [2][BS_T]

  const int nwg = gridDim.x, cpx = nwg >> 3, b = blockIdx.x;
  const int swz = (b & 7) * cpx + (b >> 3);       // 768 % 8 == 0 -> bijective
  const int bm = swz / (Nd / BN), bn = swz % (Nd / BN);  // bm-major: A panel L2-resident
  const int m0 = bm * BM, n0 = bn * BN;

  const int tid = threadIdx.x, lane = tid & 63, wid = tid >> 6;
  const int wr = wid >> 2, wc = wid & 3;          // 2x4 waves, each 128x64 output
  const int lr = lane & 15, lk = lane >> 4;

  const int n_l = tid & 255;                      // B staging: n within tile
  const int k8b = (tid >> 8) * 4;                 // first of 4 k8-rows (0 or 4)
  const int nab = n0 + n_l;

  f4 acc[8][4];
  #pragma unroll
  for (int i = 0; i < 8; ++i)
    #pragma unroll
    for (int j = 0; j < 4; ++j) acc[i][j] = {0.0f, 0.0f, 0.0f, 0.0f};

  h8 afr[4][2];           // A frags: one mi-half (4 mi x 2 ks)
  h8 bfA[2][2], bfB[2][2];// B frags: ni-half 0 (ni0-1) and 1 (ni2-3)

  // --- A staging: LDS linear dest, pre-swizzled global source; half = 2 of 4 chunks
  auto stageA = [&](int t, int buf, int half) {
    #pragma unroll
    for (int i = half * 2; i < half * 2 + 2; ++i) {
      const int c = i * THREADS + tid;            // 2048 chunks = 256 rows x 8 kb
      const int r = c >> 3, kbl = c & 7;
      const unsigned short* src = Xb + (size_t)(m0 + r) * Kd + t * BK + ((kbl ^ (r & 7)) << 3);
      __builtin_amdgcn_global_load_lds(
          (const __attribute__((address_space(1))) unsigned*)src,
          (__attribute__((address_space(3))) unsigned*)(As + buf * AS_T + c * 8),
          16, 0, 0);
    }
  };
  auto loadQW = [&](int t, int* w) {
    const int* qp = QW + (size_t)(t * 8 + k8b) * Nd + nab;
    #pragma unroll
    for (int i = 0; i < 4; ++i) w[i] = qp[(size_t)i * Nd];
  };
  auto writeB = [&](const int* w, unsigned hs2, unsigned hz2, int buf) {
    const h2 vz = __builtin_bit_cast(h2, hz2);
    const h2 vs = __builtin_bit_cast(h2, hs2);
    #pragma unroll
    for (int i = 0; i < 4; ++i) {
      const unsigned q = (unsigned)w[i];
      const int k8 = k8b + i;
      const unsigned p0 = (q & M4) | MAG;
      const unsigned p1 = ((q >> 4) & M4) | MAG;
      const unsigned p2 = ((q >> 8) & M4) | MAG;
      const unsigned p3 = ((q >> 12) & M4) | MAG;
      const h2 f0 = (__builtin_bit_cast(h2, p0) - vz) * vs;
      const h2 f1 = (__builtin_bit_cast(h2, p1) - vz) * vs;
      const h2 f2 = (__builtin_bit_cast(h2, p2) - vz) * vs;
      const h2 f3 = (__builtin_bit_cast(h2, p3) - vz) * vs;
      uint4 o;
      o.x = __builtin_bit_cast(unsigned, f0);
      o.y = __builtin_bit_cast(unsigned, f1);
      o.z = __builtin_bit_cast(unsigned, f2);
      o.w = __builtin_bit_cast(unsigned, f3);
      *(uint4*)(Bs + buf * BS_T + n_l * BK + ((k8 ^ (n_l & 7)) << 3)) = o;
    }
  };
  auto dsA = [&](int buf, int mih) {              // read afr <- mi half
    const unsigned short* Ab = As + buf * AS_T;
    #pragma unroll
    for (int mi4 = 0; mi4 < 4; ++mi4) {
      const int r = wr * 128 + (mih * 4 + mi4) * 16 + lr;
      #pragma unroll
      for (int ks = 0; ks < 2; ++ks) {
        const int kb = ks * 4 + lk;
        afr[mi4][ks] = *(const h8*)&Ab[r * BK + ((kb ^ (r & 7)) << 3)];
      }
    }
  };
  auto dsB = [&](int buf, int nih, h8 (&dst)[2][2]) {
    const unsigned short* Bb = Bs + buf * BS_T;
    #pragma unroll
    for (int ni2 = 0; ni2 < 2; ++ni2) {
      const int cc = wc * 64 + (nih * 2 + ni2) * 16 + lr;
      #pragma unroll
      for (int ks = 0; ks < 2; ++ks) {
        const int kb = ks * 4 + lk;
        dst[ni2][ks] = *(const h8*)&Bb[cc * BK + ((kb ^ (cc & 7)) << 3)];
      }
    }
  };
  auto mfmaQ = [&](int mih, int nih, h8 (&bfr)[2][2]) {
    __builtin_amdgcn_s_setprio(1);
    #pragma unroll
    for (int mi4 = 0; mi4 < 4; ++mi4)
      #pragma unroll
      for (int ni2 = 0; ni2 < 2; ++ni2)
        #pragma unroll
        for (int ks = 0; ks < 2; ++ks)
          acc[mih * 4 + mi4][nih * 2 + ni2] =
            __builtin_amdgcn_mfma_f32_16x16x32_f16(afr[mi4][ks], bfr[ni2][ks],
                                                   acc[mih * 4 + mi4][nih * 2 + ni2], 0, 0, 0);
    __builtin_amdgcn_s_setprio(0);
  };
  auto makeH = [&](float s, int z32, unsigned& hs2, unsigned& hz2) {
    const int z = (z32 >> ((nab & 7) * 4)) & 15;
    hz2 = (0x6400u + (unsigned)z + 1u) * 0x10001u;       // fp16(1025+z), exact
    hs2 = (unsigned)__builtin_bit_cast(unsigned short, (_Float16)s) * 0x10001u;
  };

  int bw[4];
  float sN; int zN;
  unsigned hsC, hzC;

  // ---- prologue: SZ(0), QW(0) first (oldest), then A(0) DMA; stage tile 0 into buf0
  {
    const float s0 = SC[(size_t)0 * Nd + nab];
    const int z0 = QZ[(nab >> 3)];
    loadQW(0, bw);
    stageA(0, 0, 0); stageA(0, 0, 1);
    makeH(s0, z0, hsC, hzC);
    writeB(bw, hsC, hzC, 0);            // auto-waits QW, leaves A in flight
    WAIT_LGKM0; WAIT_VM0; SBAR;
  }

  for (int u = 0; u < TK / 2; ++u) {
    const bool ns = (u < TK / 2 - 1);

    // ======== even tile e=2u: compute buf0, stage tile 2u+1 -> buf1 (group u)
    // ph0
    dsA(0, 0); dsB(0, 0, bfA);
    loadQW(2 * u + 1, bw);              // oldest VMEM this tile
    stageA(2 * u + 1, 1, 0);
    SBAR; mfmaQ(0, 0, bfA); SBAR;
    // ph1
    dsB(0, 1, bfB);
    stageA(2 * u + 1, 1, 1);
    SBAR; mfmaQ(0, 1, bfB); SBAR;
    // ph2
    dsA(0, 1);
    SBAR; mfmaQ(1, 0, bfA); SBAR;
    // ph3
    writeB(bw, hsC, hzC, 1);            // auto-wait drains QW only (A newer)
    mfmaQ(1, 1, bfB);
    WAIT_LGKM0; WAIT_VM0; SBAR;         // A(2u+1) + B writes complete

    // ======== odd tile o=2u+1: compute buf1, stage tile 2u+2 -> buf0 (group u+1)
    // ph0
    dsA(1, 0); dsB(1, 0, bfA);
    if (ns) {
      loadQW(2 * u + 2, bw);
      sN = SC[(size_t)(u + 1) * Nd + nab];
      zN = QZ[(size_t)(u + 1) * (Nd / 8) + (nab >> 3)];
      stageA(2 * u + 2, 0, 0);
    }
    SBAR; mfmaQ(0, 0, bfA); SBAR;
    // ph1
    dsB(1, 1, bfB);
    if (ns) stageA(2 * u + 2, 0, 1);
    SBAR; mfmaQ(0, 1, bfB); SBAR;
    // ph2
    dsA(1, 1);
    SBAR; mfmaQ(1, 0, bfA); SBAR;
    // ph3
    if (ns) {
      unsigned nhs, nhz;
      makeH(sN, zN, nhs, nhz);          // auto-waits SZ (+QW older)
      writeB(bw, nhs, nhz, 0);
      hsC = nhs; hzC = nhz;
    }
    mfmaQ(1, 1, bfB);
    WAIT_LGKM0; WAIT_VM0; SBAR;
  }

  // ---- epilogue: C/D layout col = lane&15, row = (lane>>4)*4 + j
  #pragma unroll
  for (int ni = 0; ni < 4; ++ni) {
    const int gn = n0 + wc * 64 + ni * 16 + lr;
    const float bv = BS[gn];
    #pragma unroll
    for (int mi = 0; mi < 8; ++mi) {
      const int gm = m0 + wr * 128 + mi * 16 + (lk << 2);
      #pragma unroll
      for (int j = 0; j < 4; ++j)
        OUT[(size_t)(gm + j) * Nd + gn] = acc[mi][ni][j] + bv;
    }
  }
}

// ---------------- fallback (no workspace): round-8 inline-dequant kernel ----------------
__global__ __launch_bounds__(256, 2)
void qgemm_fb(const float* __restrict__ X,
              const int* __restrict__ QW, const int* __restrict__ QZ,
              const float* __restrict__ SC, const float* __restrict__ BS,
              float* __restrict__ OUT)
{
  constexpr int FBM = 256, FBN = 128;
  constexpr int FAS = FBM * BK;
  extern __shared__ char smem[];
  unsigned short* As = (unsigned short*)smem;
  unsigned short* Bs = (unsigned short*)(smem + 2 * FAS * 2);

  const int nwg = gridDim.x, cpx = nwg >> 3, b = blockIdx.x;
  const int swz = (b & 7) * cpx + (b >> 3);
  const int bm = swz / (Nd / FBN), bn = swz % (Nd / FBN);
  const int m0 = bm * FBM, n0 = bn * FBN;
  const int tid = threadIdx.x, lane = tid & 63, wid = tid >> 6;
  const int wr = wid >> 1, wc = wid & 1;
  const int n_l = tid & 127;
  const int k8b = (tid >> 7) * 4;
  const int nab = n0 + n_l;

  f4 acc[8][4];
  #pragma unroll
  for (int i = 0; i < 8; ++i)
    #pragma unroll
    for (int j = 0; j < 4; ++j) acc[i][j] = {0.0f, 0.0f, 0.0f, 0.0f};

  auto stageA_f = [&](int t, int buf) {
    #pragma unroll
    for (int i = 0; i < 8; ++i) {
      const int c = i * 256 + tid;
      const int r = c >> 3, kbl = c & 7;
      const f4* src = (const f4*)(X + (size_t)(m0 + r) * Kd + t * BK + ((kbl ^ (r & 7)) << 3));
      f4 a = src[0], bb = src[1];
      uint4 o;
      o.x = pkrtz(a[0], bb[0]); o.y = pkrtz(a[1], bb[1]);
      o.z = pkrtz(a[2], bb[2]); o.w = pkrtz(a[3], bb[3]);
      *(uint4*)(As + buf * FAS + c * 8) = o;
    }
  };
  auto loadB = [&](int t, int* w, unsigned& hs2, unsigned& hz2) {
    const int* qp = QW + (size_t)(t * 8 + k8b) * Nd + nab;
    #pragma unroll
    for (int i = 0; i < 4; ++i) w[i] = qp[(size_t)i * Nd];
    const int g = t >> 1;
    const float s = SC[(size_t)g * Nd + nab];
    const int z32 = QZ[(size_t)g * (Nd / 8) + (nab >> 3)];
    const int z = (z32 >> ((nab & 7) * 4)) & 15;
    hz2 = (0x6400u + (unsigned)z + 1u) * 0x10001u;
    hs2 = (unsigned)__builtin_bit_cast(unsigned short, (_Float16)s) * 0x10001u;
  };
  auto writeB = [&](const int* w, unsigned hs2, unsigned hz2) {
    const h2 vz = __builtin_bit_cast(h2, hz2);
    const h2 vs = __builtin_bit_cast(h2, hs2);
    #pragma unroll
    for (int i = 0; i < 4; ++i) {
      const unsigned q = (unsigned)w[i];
      const int k8 = k8b + i;
      const unsigned p0 = (q & M4) | MAG;
      const unsigned p1 = ((q >> 4) & M4) | MAG;
      const unsigned p2 = ((q >> 8) & M4) | MAG;
      const unsigned p3 = ((q >> 12) & M4) | MAG;
      const h2 f0 = (__builtin_bit_cast(h2, p0) - vz) * vs;
      const h2 f1 = (__builtin_bit_cast(h2, p1) - vz) * vs;
      const h2 f2 = (__builtin_bit_cast(h2, p2) - vz) * vs;
      const h2 f3 = (__builtin_bit_cast(h2, p3) - vz) * vs;
      uint4 o;
      o.x = __builtin_bit_cast(unsigned, f0);
      o.y = __builtin_bit_cast(unsigned, f1);
      o.z = __builtin_bit_cast(unsigned, f2);
      o.w = __builtin_bit_cast(unsigned, f3);
      *(uint4*)(Bs + n_l * BK + ((k8 ^ (n_l & 7)) << 3)) = o;
    }
  };
  auto mfma_tile = [&](int cb) {
    const unsigned short* Ab = As + cb * FAS;
    #pragma unroll
    for (int ks = 0; ks < 2; ++ks) {
      h8 af[8], bf[4];
      const int kb = ks * 4 + (lane >> 4);
      #pragma unroll
      for (int mi = 0; mi < 8; ++mi) {
        const int r = wr * 128 + mi * 16 + (lane & 15);
        af[mi] = *(const h8*)&Ab[r * BK + ((kb ^ (r & 7)) << 3)];
      }
      #pragma unroll
      for (int ni = 0; ni < 4; ++ni) {
        const int cc = wc * 64 + ni * 16 + (lane & 15);
        bf[ni] = *(const h8*)&Bs[cc * BK + ((kb ^ (cc & 7)) << 3)];
      }
      #pragma unroll
      for (int mi = 0; mi < 8; ++mi)
        #pragma unroll
        for (int ni = 0; ni < 4; ++ni)
          acc[mi][ni] = __builtin_amdgcn_mfma_f32_16x16x32_f16(af[mi], bf[ni], acc[mi][ni], 0, 0, 0);
    }
  };

  int bw[4]; unsigned sHS, sHZ;
  int nbw[4]; unsigned nHS, nHZ;
  stageA_f(0, 0);
  loadB(0, bw, sHS, sHZ);
  writeB(bw, sHS, sHZ);
  __syncthreads();
  for (int t = 0; t < TK; ++t) {
    const int cb = t & 1;
    if (t + 1 < TK) loadB(t + 1, nbw, nHS, nHZ);
    mfma_tile(cb);
    __syncthreads();
    if (t + 1 < TK) {
      stageA_f(t + 1, cb ^ 1);
      writeB(nbw, nHS, nHZ);
    }
    __syncthreads();
  }
  #pragma unroll
  for (int ni = 0; ni < 4; ++ni) {
    const int gn = n0 + wc * 64 + ni * 16 + (lane & 15);
    const float bv = BS[gn];
    #pragma unroll
    for (int mi = 0; mi < 8; ++mi) {
      const int gm = m0 + wr * 128 + mi * 16 + ((lane >> 4) << 2);
      #pragma unroll
      for (int j = 0; j < 4; ++j)
        OUT[(size_t)(gm + j) * Nd + gn] = acc[mi][ni][j] + bv;
    }
  }
}
} // namespace

extern "C" void kernel_launch(void* const* d_in, const int* in_sizes, int n_in,
                              void* d_out, int out_size, void* d_ws, size_t ws_size,
                              hipStream_t stream) {
  const float* x  = (const float*)d_in[0];
  const int*   qw = (const int*)d_in[1];
  const int*   qz = (const int*)d_in[2];
  const float* sc = (const float*)d_in[3];
  const float* bs = (const float*)d_in[4];
  float* out = (float*)d_out;

  (void)hipFuncSetAttribute((const void*)qgemm8,
                            hipFuncAttributeMaxDynamicSharedMemorySize, LDS_BYTES);
  (void)hipFuncSetAttribute((const void*)qgemm_fb,
                            hipFuncAttributeMaxDynamicSharedMemorySize, (2 * 256 * BK + 128 * BK) * 2);

  if (ws_size >= A_BYTES) {
    unsigned short* xh = (unsigned short*)d_ws;
    const int n8 = Md * Kd / 8;
    cvtA_perm<<<2048, 256, 0, stream>>>(x, xh, n8);
    dim3 grid((Md / BM) * (Nd / BN));   // 16 * 48 = 768
    qgemm8<<<grid, dim3(THREADS), LDS_BYTES, stream>>>(xh, qw, qz, sc, bs, out);
  } else {
    dim3 grid((Md / 256) * (Nd / 128)); // 16 * 96 = 1536
    qgemm_fb<<<grid, dim3(256), (2 * 256 * BK + 128 * BK) * 2, stream>>>(x, qw, qz, sc, bs, out);
  }
}